// Round 17
// baseline (86.333 us; speedup 1.0000x reference)
//
#include <hip/hip_runtime.h>
#include <hip/hip_bf16.h>
#include <stdint.h>

// Problem constants: B=4, deep_C=256, shallow_C=64, H=W=64, N=4096, qk_C=16.
#define LOG2E 1.44269504088896340736f

typedef _Float16 f16x8  __attribute__((ext_vector_type(8)));
typedef __bf16   bf16x8 __attribute__((ext_vector_type(8)));
typedef float    f32x16 __attribute__((ext_vector_type(16)));

__device__ __forceinline__ uint32_t pack_f16_rn(float a, float b) {
    uint16_t ua = __builtin_bit_cast(uint16_t, (_Float16)a);   // v_cvt_f16_f32 RNE
    uint16_t ub = __builtin_bit_cast(uint16_t, (_Float16)b);
    return (uint32_t)ua | ((uint32_t)ub << 16);
}
__device__ __forceinline__ uint32_t pack_bf2(float a, float b) {
    uint16_t ua = __builtin_bit_cast(uint16_t, (__bf16)a);     // RNE
    uint16_t ub = __builtin_bit_cast(uint16_t, (__bf16)b);
    return (uint32_t)ua | ((uint32_t)ub << 16);
}

// ------- Fused prepass: q (0..63) | k (64..127) | vconv (128..383) -------
// q/k SPLIT into separate blocks (r16 had both in one thread = 2048 serial
// FMAs on only 64 blocks; now 16 FMA/iter on 128 blocks -> ~2x faster).
//   Qb: [b][n][16 fp16], q PRE-SCALED by LOG2E.
//   Kb3 slice (32 keys, fp16): addr_u16 = (b*128+slice)*512 + (n&31)*8;
//     +256 for chans 8-15.
//   Vb unit (16 B = 8 keys x 1 chan, BF16): unit =
//     (((b*8+ct)*256+kb)*2+h1)*32+c = deep[b][ct*32+c][kb*16+h1*8 .. +7].
// vconv LDS-transposed: both sides coalesced (1 KB/wave), pad-516 tile.
__global__ void __launch_bounds__(256) prepass(
    const float* __restrict__ deep, const float* __restrict__ shallow,
    const float* __restrict__ Wq, const float* __restrict__ bq,
    const float* __restrict__ Wk, const float* __restrict__ bk,
    uint16_t* __restrict__ Vb, uint16_t* __restrict__ Qb,
    uint16_t* __restrict__ Kb3) {
    __shared__ uint16_t tile[32 * 516];     // 33 KB (vconv branch only)
    const int blk = blockIdx.x;
    if (blk < 128) {
        const bool doQ = (blk < 64);         // block-uniform
        int gid = (doQ ? blk : blk - 64) * 256 + threadIdx.x;  // b*4096+n
        int b = gid >> 12;
        int n = gid & 4095;
        const float* sp = shallow + (size_t)b * 64 * 4096 + n;
        const float* W  = doQ ? Wq : Wk;
        const float* bi = doQ ? bq : bk;
        float v[16];
#pragma unroll
        for (int o = 0; o < 16; ++o) v[o] = bi[o];
#pragma unroll 4
        for (int c = 0; c < 64; ++c) {
            float s = sp[(size_t)c * 4096];
#pragma unroll
            for (int o = 0; o < 16; ++o) v[o] = fmaf(W[o * 64 + c], s, v[o]);
        }
        if (doQ) {
            uint16_t* qr = Qb + (size_t)gid * 16;
            *(uint4*)(qr)     = make_uint4(pack_f16_rn(v[0]*LOG2E,  v[1]*LOG2E),
                                           pack_f16_rn(v[2]*LOG2E,  v[3]*LOG2E),
                                           pack_f16_rn(v[4]*LOG2E,  v[5]*LOG2E),
                                           pack_f16_rn(v[6]*LOG2E,  v[7]*LOG2E));
            *(uint4*)(qr + 8) = make_uint4(pack_f16_rn(v[8]*LOG2E,  v[9]*LOG2E),
                                           pack_f16_rn(v[10]*LOG2E, v[11]*LOG2E),
                                           pack_f16_rn(v[12]*LOG2E, v[13]*LOG2E),
                                           pack_f16_rn(v[14]*LOG2E, v[15]*LOG2E));
        } else {
            uint16_t* kr = Kb3 + (size_t)(b * 128 + (n >> 5)) * 512 + (size_t)(n & 31) * 8;
            *(uint4*)(kr)       = make_uint4(pack_f16_rn(v[0],  v[1]),  pack_f16_rn(v[2],  v[3]),
                                             pack_f16_rn(v[4],  v[5]),  pack_f16_rn(v[6],  v[7]));
            *(uint4*)(kr + 256) = make_uint4(pack_f16_rn(v[8],  v[9]),  pack_f16_rn(v[10], v[11]),
                                             pack_f16_rn(v[12], v[13]), pack_f16_rn(v[14], v[15]));
        }
    } else {
        // vconv: block = (b, ct, kseg of 512 keys); [32 c][512 k] bf16 tile
        const int vb_id = blk - 128;         // 0..255
        const int b  = vb_id >> 6;
        const int ct = (vb_id >> 3) & 7;
        const int kseg = vb_id & 7;
        const int tid = threadIdx.x;
        const int k4 = tid & 63;
        const int cb = tid >> 6;             // 0..3 (constant per wave)
        const size_t dbase = ((size_t)(b * 256 + ct * 32) * 4096) + kseg * 512;
#pragma unroll
        for (int p = 0; p < 16; ++p) {
            int c   = (p & 7) * 4 + cb;
            int key = (p >> 3) * 256 + k4 * 4;
            float4 f = *(const float4*)(deep + dbase + (size_t)c * 4096 + key);
            *(uint2*)&tile[c * 516 + key] =
                make_uint2(pack_bf2(f.x, f.y), pack_bf2(f.z, f.w));
        }
        __syncthreads();
        const int c   = tid & 31;
        const int h1  = (tid >> 5) & 1;
        const int kb0 = tid >> 6;            // 0..3
#pragma unroll
        for (int p2 = 0; p2 < 8; ++p2) {
            int kb = p2 * 4 + kb0;           // 0..31 within kseg
            const uint16_t* t = &tile[c * 516 + kb * 16 + h1 * 8];
            uint2 lo = *(const uint2*)(t);
            uint2 hi = *(const uint2*)(t + 4);
            size_t u = (((size_t)((b * 8 + ct) * 256 + kseg * 32 + kb) * 2) + h1) * 32 + c;
            ((uint4*)Vb)[u] = make_uint4(lo.x, lo.y, hi.x, hi.y);
        }
    }
}

// ---------------- Main fused flash-attention kernel ----------------------
// r16 structure (16 waves, 4/SIMD, dual-axis split, fp16 QK + bf16 P/V,
// LBAR — 53.3 us) with BARRIERS HALVED: 4-bank Pl (128 KB) lets one
// pair-iteration produce P(2s2+2),P(2s2+3) while consuming P(2s2),P(2s2+1)
// — banks provably disjoint — so waves re-converge once per TWO supersteps
// (8 barriers instead of 16; convergence convoying was the leading
// unaccounted wall term: wall 8.0k cy/ss vs max shared pipe 3.8k).
__global__ void __launch_bounds__(1024, 4) attn_main(
    const uint16_t* __restrict__ Qb, const uint16_t* __restrict__ Kb3,
    const uint16_t* __restrict__ Vb, const float* __restrict__ deep,
    const float* __restrict__ gamma, float* __restrict__ out) {
    const int lane = threadIdx.x & 63;
    const int w    = threadIdx.x >> 6;   // 0..15
    const int ks   = w & 7;              // produce key-slice / PV chan-tile
    const int sel  = w >> 3;             // produce query-half / PV key-half
    const int col  = lane & 31;
    const int h1   = lane >> 5;

    // XCD-locality: one batch per XCD pair (V slice 2 MB < 4 MB L2/XCD).
    const int bid = blockIdx.x;
    const int xcd = bid & 7;
    const int b   = xcd >> 1;
    const int qt  = ((bid >> 3) << 1) + (xcd & 1);   // 0..63
    const int n0q = qt * 64;

    __shared__ uint4 Pl[4][2][16][2][32];  // bank, qh, frag, h1', col = 128 KB
    __shared__ float Lf[2][16][32];        // qh, ks*2+h1, col         =   4 KB

    // Q B-frag for this wave's query half (fp16, pre-scaled by LOG2E)
    const uint16_t* qrow = Qb + ((size_t)(b * 4096 + n0q + sel * 32 + col)) * 16;
    uint4 ubq = *(const uint4*)(qrow + h1 * 8);

    const uint16_t* kbase = Kb3 + (size_t)b * 65536 + (size_t)ks * 512
                                + (size_t)lane * 8;                  // + ss*4096
    // PV: chan-tile ks, key-half sel (frags sel*8 .. sel*8+7)
    const uint16_t* vlane = Vb + (size_t)(b * 8 + ks) * 131072
                               + (size_t)sel * 4096
                               + (size_t)h1 * 256 + (size_t)col * 8; // + ss*8192 + j*512

    f32x16 acc0 = {0,0,0,0,0,0,0,0,0,0,0,0,0,0,0,0};  // qh0, key-half sel
    f32x16 acc1 = {0,0,0,0,0,0,0,0,0,0,0,0,0,0,0,0};  // qh1, key-half sel
    float lacc = 0.0f;                   // private l partial (qh=sel, ks, h1)
    uint4 uk;                            // K frag for next produce

    // produce P(s) for (ks, qh=sel) -> Pl[s&3][sel]; reloads K(s+1) after use.
    auto qk_softmax = [&](int s) {
        const int pr = s & 3;
        f16x8 ak = __builtin_bit_cast(f16x8, uk);
        f16x8 bq = __builtin_bit_cast(f16x8, ubq);
        f32x16 e = {0,0,0,0,0,0,0,0,0,0,0,0,0,0,0,0};
        e = __builtin_amdgcn_mfma_f32_32x32x16_f16(ak, bq, e, 0, 0, 0);
        const int sn = (s < 15) ? s + 1 : s;   // K(s+1) reload after last use
        uk = *(const uint4*)(kbase + (size_t)sn * 4096);
        float p[16];
#pragma unroll
        for (int r = 0; r < 16; ++r) p[r] = exp2f(e[r]);   // Q pre-scaled
        float t0 = (p[0] + p[1]) + (p[2] + p[3]);
        float t1 = (p[4] + p[5]) + (p[6] + p[7]);
        float t2 = (p[8] + p[9]) + (p[10] + p[11]);
        float t3 = (p[12] + p[13]) + (p[14] + p[15]);
        lacc += (t0 + t1) + (t2 + t3);
        uint32_t pk0 = pack_bf2(p[0],  p[1]),  pk1 = pack_bf2(p[2],  p[3]);
        uint32_t pk2 = pack_bf2(p[4],  p[5]),  pk3 = pack_bf2(p[6],  p[7]);
        uint32_t pk4 = pack_bf2(p[8],  p[9]),  pk5 = pack_bf2(p[10], p[11]);
        uint32_t pk6 = pack_bf2(p[12], p[13]), pk7 = pack_bf2(p[14], p[15]);
        ((uint2*)&Pl[pr][sel][2 * ks    ][0][col])[h1] = make_uint2(pk0, pk1);
        ((uint2*)&Pl[pr][sel][2 * ks    ][1][col])[h1] = make_uint2(pk2, pk3);
        ((uint2*)&Pl[pr][sel][2 * ks + 1][0][col])[h1] = make_uint2(pk4, pk5);
        ((uint2*)&Pl[pr][sel][2 * ks + 1][1][col])[h1] = make_uint2(pk6, pk7);
    };

// LDS-only barrier: Pl visibility without draining global loads (vmcnt
// stays counted — K/V prefetch ride across).
#define LBAR()                                                      \
    {                                                               \
        asm volatile("s_waitcnt lgkmcnt(0)" ::: "memory");          \
        __builtin_amdgcn_s_barrier();                               \
    }
// PV for superstep ss from Pl bank (ss&3), V in vr.
#define PVSTEP(ss, vr)                                              \
    {                                                               \
        const int bk_ = (ss) & 3;                                   \
        __builtin_amdgcn_s_setprio(1);                              \
        _Pragma("unroll")                                           \
        for (int j = 0; j < 8; ++j) {                               \
            const int f = sel * 8 + j;                              \
            uint4 pb0 = Pl[bk_][0][f][h1][col];                     \
            uint4 pb1 = Pl[bk_][1][f][h1][col];                     \
            bf16x8 av = __builtin_bit_cast(bf16x8, vr[j]);          \
            acc0 = __builtin_amdgcn_mfma_f32_32x32x16_bf16(         \
                av, __builtin_bit_cast(bf16x8, pb0), acc0, 0, 0, 0);\
            acc1 = __builtin_amdgcn_mfma_f32_32x32x16_bf16(         \
                av, __builtin_bit_cast(bf16x8, pb1), acc1, 0, 0, 0);\
        }                                                           \
        __builtin_amdgcn_s_setprio(0);                              \
    }

    // ---- prologue: produce P(0), P(1) ----
    uk = *(const uint4*)(kbase);
    qk_softmax(0);
    qk_softmax(1);
    LBAR();                                 // barrier 0

    // ---- main loop: 8 pair-iterations, ONE barrier each ----
    for (int s2 = 0; s2 < 8; ++s2) {
        const int ss0 = s2 * 2;
        const int ss1 = ss0 + 1;
        uint4 vr[8];
        // superstep ss0: V issue, produce(ss0+2), PV(ss0)
        const uint16_t* vss0 = vlane + (size_t)ss0 * 8192;
#pragma unroll
        for (int j = 0; j < 8; ++j) vr[j] = *(const uint4*)(vss0 + j * 512);
        if (ss0 + 2 < 16) qk_softmax(ss0 + 2);
        PVSTEP(ss0, vr);
        // superstep ss1: V issue, produce(ss0+3), PV(ss1)
        const uint16_t* vss1 = vlane + (size_t)ss1 * 8192;
#pragma unroll
        for (int j = 0; j < 8; ++j) vr[j] = *(const uint4*)(vss1 + j * 512);
        if (ss0 + 3 < 16) qk_softmax(ss0 + 3);
        PVSTEP(ss1, vr);
        LBAR();                             // barriers 1..8
    }

    // ---- key-half partial exchange (reuses Pl space — safe after last barrier)
    Lf[sel][ks * 2 + h1][col] = lacc;
    float* Ex = (float*)&Pl[0][0][0][0][0];     // 16 waves x 64 lanes x 16 f32
    float* myEx = Ex + ((size_t)w * 64 + lane) * 16;
    if (w < 8) {
#pragma unroll
        for (int r = 0; r < 16; ++r) myEx[r] = acc1[r];
    } else {
#pragma unroll
        for (int r = 0; r < 16; ++r) myEx[r] = acc0[r];
    }
    LBAR();                                  // final barrier
    const float* pEx = Ex + ((size_t)(w ^ 8) * 64 + lane) * 16;
    float l = 0.0f;
#pragma unroll
    for (int j = 0; j < 16; ++j) l += Lf[sel][j][col];
    const float gr = gamma[0] / l;

    if (w < 8) {                             // finalize (ct=ks, qh0)
#pragma unroll
        for (int r = 0; r < 16; ++r) {
            float a = acc0[r] + pEx[r];
            const int crow = (r & 3) + 8 * (r >> 2) + 4 * h1;
            size_t i0 = (size_t)(b * 256 + ks * 32 + crow) * 4096 + n0q + col;
            out[i0] = fmaf(gr, a, deep[i0]);
        }
    } else {                                 // finalize (ct=ks, qh1)
#pragma unroll
        for (int r = 0; r < 16; ++r) {
            float a = acc1[r] + pEx[r];
            const int crow = (r & 3) + 8 * (r >> 2) + 4 * h1;
            size_t i1 = (size_t)(b * 256 + ks * 32 + crow) * 4096 + n0q + 32 + col;
            out[i1] = fmaf(gr, a, deep[i1]);
        }
    }
#undef PVSTEP
#undef LBAR
}

extern "C" void kernel_launch(void* const* d_in, const int* in_sizes, int n_in,
                              void* d_out, int out_size, void* d_ws, size_t ws_size,
                              hipStream_t stream) {
    const float* deep    = (const float*)d_in[0];
    const float* shallow = (const float*)d_in[1];
    const float* Wq      = (const float*)d_in[2];
    const float* bq      = (const float*)d_in[3];
    const float* Wk      = (const float*)d_in[4];
    const float* bk      = (const float*)d_in[5];
    const float* gamma   = (const float*)d_in[6];
    float* out = (float*)d_out;

    // ws layout: Vb bf16 swizzled (8 MiB) | Qb (512 KiB @8M) | Kb3 (512 KiB @9M)
    uint16_t* Vb  = (uint16_t*)d_ws;
    uint16_t* Qb  = (uint16_t*)((char*)d_ws + (size_t)8 * 1024 * 1024);
    uint16_t* Kb3 = (uint16_t*)((char*)d_ws + (size_t)9 * 1024 * 1024);

    hipLaunchKernelGGL(prepass, dim3(384), dim3(256), 0, stream,
                       deep, shallow, Wq, bq, Wk, bk, Vb, Qb, Kb3);
    hipLaunchKernelGGL(attn_main, dim3(256), dim3(1024), 0, stream,
                       Qb, Kb3, Vb, deep, gamma, out);
}

// Round 18
// 62.290 us; speedup vs baseline: 1.3860x; 1.3860x over previous
//
#include <hip/hip_runtime.h>
#include <hip/hip_bf16.h>
#include <stdint.h>

// Problem constants: B=4, deep_C=256, shallow_C=64, H=W=64, N=4096, qk_C=16.
#define LOG2E 1.44269504088896340736f

typedef _Float16 f16x8  __attribute__((ext_vector_type(8)));
typedef __bf16   bf16x8 __attribute__((ext_vector_type(8)));
typedef float    f32x16 __attribute__((ext_vector_type(16)));

__device__ __forceinline__ uint32_t pack_f16_rn(float a, float b) {
    uint16_t ua = __builtin_bit_cast(uint16_t, (_Float16)a);   // v_cvt_f16_f32 RNE
    uint16_t ub = __builtin_bit_cast(uint16_t, (_Float16)b);
    return (uint32_t)ua | ((uint32_t)ub << 16);
}
__device__ __forceinline__ uint32_t pack_bf2(float a, float b) {
    uint16_t ua = __builtin_bit_cast(uint16_t, (__bf16)a);     // RNE
    uint16_t ub = __builtin_bit_cast(uint16_t, (__bf16)b);
    return (uint32_t)ua | ((uint32_t)ub << 16);
}

// ------- Fused prepass: q (0..63) | k (64..127) | vconv (128..383) -------
// q/k SPLIT into separate blocks (16 FMA/iter on 128 blocks vs r16's
// 32 FMA/iter on 64 blocks -> ~2x shorter qk critical path).
//   Qb: [b][n][16 fp16], q PRE-SCALED by LOG2E.
//   Kb3 slice (32 keys, fp16): addr_u16 = (b*128+slice)*512 + (n&31)*8;
//     +256 for chans 8-15.
//   Vb unit (16 B = 8 keys x 1 chan, BF16): unit =
//     (((b*8+ct)*256+kb)*2+h1)*32+c = deep[b][ct*32+c][kb*16+h1*8 .. +7].
// vconv LDS-transposed: both sides coalesced (1 KB/wave), pad-516 tile.
__global__ void __launch_bounds__(256) prepass(
    const float* __restrict__ deep, const float* __restrict__ shallow,
    const float* __restrict__ Wq, const float* __restrict__ bq,
    const float* __restrict__ Wk, const float* __restrict__ bk,
    uint16_t* __restrict__ Vb, uint16_t* __restrict__ Qb,
    uint16_t* __restrict__ Kb3) {
    __shared__ uint16_t tile[32 * 516];     // 33 KB (vconv branch only)
    const int blk = blockIdx.x;
    if (blk < 128) {
        const bool doQ = (blk < 64);         // block-uniform
        int gid = (doQ ? blk : blk - 64) * 256 + threadIdx.x;  // b*4096+n
        int b = gid >> 12;
        int n = gid & 4095;
        const float* sp = shallow + (size_t)b * 64 * 4096 + n;
        const float* W  = doQ ? Wq : Wk;
        const float* bi = doQ ? bq : bk;
        float v[16];
#pragma unroll
        for (int o = 0; o < 16; ++o) v[o] = bi[o];
#pragma unroll 4
        for (int c = 0; c < 64; ++c) {
            float s = sp[(size_t)c * 4096];
#pragma unroll
            for (int o = 0; o < 16; ++o) v[o] = fmaf(W[o * 64 + c], s, v[o]);
        }
        if (doQ) {
            uint16_t* qr = Qb + (size_t)gid * 16;
            *(uint4*)(qr)     = make_uint4(pack_f16_rn(v[0]*LOG2E,  v[1]*LOG2E),
                                           pack_f16_rn(v[2]*LOG2E,  v[3]*LOG2E),
                                           pack_f16_rn(v[4]*LOG2E,  v[5]*LOG2E),
                                           pack_f16_rn(v[6]*LOG2E,  v[7]*LOG2E));
            *(uint4*)(qr + 8) = make_uint4(pack_f16_rn(v[8]*LOG2E,  v[9]*LOG2E),
                                           pack_f16_rn(v[10]*LOG2E, v[11]*LOG2E),
                                           pack_f16_rn(v[12]*LOG2E, v[13]*LOG2E),
                                           pack_f16_rn(v[14]*LOG2E, v[15]*LOG2E));
        } else {
            uint16_t* kr = Kb3 + (size_t)(b * 128 + (n >> 5)) * 512 + (size_t)(n & 31) * 8;
            *(uint4*)(kr)       = make_uint4(pack_f16_rn(v[0],  v[1]),  pack_f16_rn(v[2],  v[3]),
                                             pack_f16_rn(v[4],  v[5]),  pack_f16_rn(v[6],  v[7]));
            *(uint4*)(kr + 256) = make_uint4(pack_f16_rn(v[8],  v[9]),  pack_f16_rn(v[10], v[11]),
                                             pack_f16_rn(v[12], v[13]), pack_f16_rn(v[14], v[15]));
        }
    } else {
        // vconv: block = (b, ct, kseg of 512 keys); [32 c][512 k] bf16 tile
        const int vb_id = blk - 128;         // 0..255
        const int b  = vb_id >> 6;
        const int ct = (vb_id >> 3) & 7;
        const int kseg = vb_id & 7;
        const int tid = threadIdx.x;
        const int k4 = tid & 63;
        const int cb = tid >> 6;             // 0..3 (constant per wave)
        const size_t dbase = ((size_t)(b * 256 + ct * 32) * 4096) + kseg * 512;
#pragma unroll
        for (int p = 0; p < 16; ++p) {
            int c   = (p & 7) * 4 + cb;
            int key = (p >> 3) * 256 + k4 * 4;
            float4 f = *(const float4*)(deep + dbase + (size_t)c * 4096 + key);
            *(uint2*)&tile[c * 516 + key] =
                make_uint2(pack_bf2(f.x, f.y), pack_bf2(f.z, f.w));
        }
        __syncthreads();
        const int c   = tid & 31;
        const int h1  = (tid >> 5) & 1;
        const int kb0 = tid >> 6;            // 0..3
#pragma unroll
        for (int p2 = 0; p2 < 8; ++p2) {
            int kb = p2 * 4 + kb0;           // 0..31 within kseg
            const uint16_t* t = &tile[c * 516 + kb * 16 + h1 * 8];
            uint2 lo = *(const uint2*)(t);
            uint2 hi = *(const uint2*)(t + 4);
            size_t u = (((size_t)((b * 8 + ct) * 256 + kseg * 32 + kb) * 2) + h1) * 32 + c;
            ((uint4*)Vb)[u] = make_uint4(lo.x, lo.y, hi.x, hi.y);
        }
    }
}

// ---------------- Main fused flash-attention kernel ----------------------
// EXACT r16 attn_main (measured best: 53.3 us; r17's 4-bank barrier-halving
// spilled ~110 MB scratch and regressed to 86 us — any schedule extension
// that lengthens live ranges across a produce+PV pair blows the 128-VGPR
// cap). 16 waves (4/SIMD), dual-axis split, fp16 QK + bf16 P/V, LBAR.
//   wave w = (ks=w&7, sel=w>>3):
//   produce: key-slice ks, query-half sel -> Pl[(s+1)&1][sel][2ks..2ks+1].
//   PV: chan-tile ks, key-half sel (8 V frags, 16 P reads, 16 bf16 MFMAs).
// Epilogue: key-half partial exchange via Pl space.
__global__ void __launch_bounds__(1024, 4) attn_main(
    const uint16_t* __restrict__ Qb, const uint16_t* __restrict__ Kb3,
    const uint16_t* __restrict__ Vb, const float* __restrict__ deep,
    const float* __restrict__ gamma, float* __restrict__ out) {
    const int lane = threadIdx.x & 63;
    const int w    = threadIdx.x >> 6;   // 0..15
    const int ks   = w & 7;              // produce key-slice / PV chan-tile
    const int sel  = w >> 3;             // produce query-half / PV key-half
    const int col  = lane & 31;
    const int h1   = lane >> 5;

    // XCD-locality: one batch per XCD pair (V slice 2 MB < 4 MB L2/XCD).
    const int bid = blockIdx.x;
    const int xcd = bid & 7;
    const int b   = xcd >> 1;
    const int qt  = ((bid >> 3) << 1) + (xcd & 1);   // 0..63
    const int n0q = qt * 64;

    __shared__ uint4 Pl[2][2][16][2][32];  // par, qh, frag, h1', col  = 64 KB
    __shared__ float Lf[2][16][32];        // qh, ks*2+h1, col (final) =  4 KB

    // Q B-frag for this wave's query half (fp16, pre-scaled by LOG2E)
    const uint16_t* qrow = Qb + ((size_t)(b * 4096 + n0q + sel * 32 + col)) * 16;
    uint4 ubq = *(const uint4*)(qrow + h1 * 8);

    const uint16_t* kbase = Kb3 + (size_t)b * 65536 + (size_t)ks * 512
                                + (size_t)lane * 8;                  // + ss*4096
    // PV: chan-tile ks, key-half sel (frags sel*8 .. sel*8+7)
    const uint16_t* vlane = Vb + (size_t)(b * 8 + ks) * 131072
                               + (size_t)sel * 4096
                               + (size_t)h1 * 256 + (size_t)col * 8; // + ss*8192 + j*512

    f32x16 acc0 = {0,0,0,0,0,0,0,0,0,0,0,0,0,0,0,0};  // qh0, key-half sel
    f32x16 acc1 = {0,0,0,0,0,0,0,0,0,0,0,0,0,0,0,0};  // qh1, key-half sel
    float lacc = 0.0f;                   // private l partial (qh=sel, ks, h1)
    uint4 uk;                            // K frag for next produce

    // produce P(s) for (ks, qh=sel) -> Pl[s&1][sel]; reloads K(s+1) after use.
    auto qk_softmax = [&](int s) {
        const int pr = s & 1;
        f16x8 ak = __builtin_bit_cast(f16x8, uk);
        f16x8 bq = __builtin_bit_cast(f16x8, ubq);
        f32x16 e = {0,0,0,0,0,0,0,0,0,0,0,0,0,0,0,0};
        e = __builtin_amdgcn_mfma_f32_32x32x16_f16(ak, bq, e, 0, 0, 0);
        const int sn = (s < 15) ? s + 1 : s;   // K(s+1) reload after last use
        uk = *(const uint4*)(kbase + (size_t)sn * 4096);
        float p[16];
#pragma unroll
        for (int r = 0; r < 16; ++r) p[r] = exp2f(e[r]);   // Q pre-scaled
        float t0 = (p[0] + p[1]) + (p[2] + p[3]);
        float t1 = (p[4] + p[5]) + (p[6] + p[7]);
        float t2 = (p[8] + p[9]) + (p[10] + p[11]);
        float t3 = (p[12] + p[13]) + (p[14] + p[15]);
        lacc += (t0 + t1) + (t2 + t3);
        uint32_t pk0 = pack_bf2(p[0],  p[1]),  pk1 = pack_bf2(p[2],  p[3]);
        uint32_t pk2 = pack_bf2(p[4],  p[5]),  pk3 = pack_bf2(p[6],  p[7]);
        uint32_t pk4 = pack_bf2(p[8],  p[9]),  pk5 = pack_bf2(p[10], p[11]);
        uint32_t pk6 = pack_bf2(p[12], p[13]), pk7 = pack_bf2(p[14], p[15]);
        ((uint2*)&Pl[pr][sel][2 * ks    ][0][col])[h1] = make_uint2(pk0, pk1);
        ((uint2*)&Pl[pr][sel][2 * ks    ][1][col])[h1] = make_uint2(pk2, pk3);
        ((uint2*)&Pl[pr][sel][2 * ks + 1][0][col])[h1] = make_uint2(pk4, pk5);
        ((uint2*)&Pl[pr][sel][2 * ks + 1][1][col])[h1] = make_uint2(pk6, pk7);
    };

// LDS-only barrier: Pl visibility without draining global loads (vmcnt
// stays counted — K prefetch rides across; V is consumed within the body).
#define LBAR()                                                      \
    {                                                               \
        asm volatile("s_waitcnt lgkmcnt(0)" ::: "memory");          \
        __builtin_amdgcn_s_barrier();                               \
    }

    // ---- prologue ----
    uk = *(const uint4*)(kbase);
    qk_softmax(0);                          // Pl[0]; leaves uk=K(1)
    LBAR();                                 // barrier 0

    // ---- main loop: one LDS-barrier per superstep ----
#pragma unroll 2
    for (int ss = 0; ss < 16; ++ss) {
        const int par = ss & 1;
        // issue-early V loads for this wave's key-half (consumed after produce)
        uint4 vr[8];
        const uint16_t* vss = vlane + (size_t)ss * 8192;
#pragma unroll
        for (int j = 0; j < 8; ++j) vr[j] = *(const uint4*)(vss + j * 512);

        if (ss < 15) qk_softmax(ss + 1);    // overlaps with PV below

        __builtin_amdgcn_s_setprio(1);
#pragma unroll
        for (int j = 0; j < 8; ++j) {
            const int f = sel * 8 + j;
            uint4 pb0 = Pl[par][0][f][h1][col];
            uint4 pb1 = Pl[par][1][f][h1][col];
            bf16x8 av = __builtin_bit_cast(bf16x8, vr[j]);
            acc0 = __builtin_amdgcn_mfma_f32_32x32x16_bf16(
                av, __builtin_bit_cast(bf16x8, pb0), acc0, 0, 0, 0);
            acc1 = __builtin_amdgcn_mfma_f32_32x32x16_bf16(
                av, __builtin_bit_cast(bf16x8, pb1), acc1, 0, 0, 0);
        }
        __builtin_amdgcn_s_setprio(0);
        LBAR();                             // barriers 1..16
    }

    // ---- key-half partial exchange (reuses Pl space — safe after barrier 16)
    Lf[sel][ks * 2 + h1][col] = lacc;
    float* Ex = (float*)&Pl[0][0][0][0][0];     // 16 waves x 64 lanes x 16 f32
    float* myEx = Ex + ((size_t)w * 64 + lane) * 16;
    if (w < 8) {
#pragma unroll
        for (int r = 0; r < 16; ++r) myEx[r] = acc1[r];
    } else {
#pragma unroll
        for (int r = 0; r < 16; ++r) myEx[r] = acc0[r];
    }
    LBAR();                                  // barrier 17
    const float* pEx = Ex + ((size_t)(w ^ 8) * 64 + lane) * 16;
    float l = 0.0f;
#pragma unroll
    for (int j = 0; j < 16; ++j) l += Lf[sel][j][col];
    const float gr = gamma[0] / l;

    if (w < 8) {                             // finalize (ct=ks, qh0)
#pragma unroll
        for (int r = 0; r < 16; ++r) {
            float a = acc0[r] + pEx[r];
            const int crow = (r & 3) + 8 * (r >> 2) + 4 * h1;
            size_t i0 = (size_t)(b * 256 + ks * 32 + crow) * 4096 + n0q + col;
            out[i0] = fmaf(gr, a, deep[i0]);
        }
    } else {                                 // finalize (ct=ks, qh1)
#pragma unroll
        for (int r = 0; r < 16; ++r) {
            float a = acc1[r] + pEx[r];
            const int crow = (r & 3) + 8 * (r >> 2) + 4 * h1;
            size_t i1 = (size_t)(b * 256 + ks * 32 + crow) * 4096 + n0q + 32 + col;
            out[i1] = fmaf(gr, a, deep[i1]);
        }
    }
#undef LBAR
}

extern "C" void kernel_launch(void* const* d_in, const int* in_sizes, int n_in,
                              void* d_out, int out_size, void* d_ws, size_t ws_size,
                              hipStream_t stream) {
    const float* deep    = (const float*)d_in[0];
    const float* shallow = (const float*)d_in[1];
    const float* Wq      = (const float*)d_in[2];
    const float* bq      = (const float*)d_in[3];
    const float* Wk      = (const float*)d_in[4];
    const float* bk      = (const float*)d_in[5];
    const float* gamma   = (const float*)d_in[6];
    float* out = (float*)d_out;

    // ws layout: Vb bf16 swizzled (8 MiB) | Qb (512 KiB @8M) | Kb3 (512 KiB @9M)
    uint16_t* Vb  = (uint16_t*)d_ws;
    uint16_t* Qb  = (uint16_t*)((char*)d_ws + (size_t)8 * 1024 * 1024);
    uint16_t* Kb3 = (uint16_t*)((char*)d_ws + (size_t)9 * 1024 * 1024);

    hipLaunchKernelGGL(prepass, dim3(384), dim3(256), 0, stream,
                       deep, shallow, Wq, bq, Wk, bk, Vb, Qb, Kb3);
    hipLaunchKernelGGL(attn_main, dim3(256), dim3(1024), 0, stream,
                       Qb, Kb3, Vb, deep, gamma, out);
}